// Round 8
// baseline (188.642 us; speedup 1.0000x reference)
//
#include <hip/hip_runtime.h>
#include <hip/hip_fp16.h>

#define P_DIM 1024
#define H_DIM 256
#define L_DIM 16384
#define DT 0.001f
#define TWOPI 6.283185307179586f
#define INV2PI 0.15915494309189535f
#define WSCALE 4096.0f
#define INVS (1.0f / 4096.0f)
#define BM 128
#define BN 128
#define BK 64
#define NT 256

typedef _Float16 f16x8 __attribute__((ext_vector_type(8)));
typedef float f32x4 __attribute__((ext_vector_type(4)));

#define GPTR(p) (const __attribute__((address_space(1))) unsigned*)(p)
#define LPTR(p) (__attribute__((address_space(3))) unsigned*)(p)

union H2U { __half2 h; unsigned u; };

__device__ __forceinline__ float2 cmulf(float2 a, float2 b) {
    return make_float2(a.x * b.x - a.y * b.y, a.x * b.y + a.y * b.x);
}

// Monotonic device barrier counter. Each launch adds exactly 512 (one per block).
// Launches are serialized (single graph node), so at launch start ctr = 512*k;
// a block's add returns old in [512k, 512k+512); target = 512k + 512.
__device__ unsigned g_ctr = 0;

// Single dispatch, R3 pipeline verbatim:
//   phase 1: W2[h][p] = fp16(4096*C*s*B)  (R2-prep expression sequence, verbatim)
//   device-scope barrier (atomic counter + fences, bounded spin)
//   phase 2: R3 main loop verbatim (DMA A from W2, VGEN fp16(V), 16x16x32 f16 MFMA)
__global__ __launch_bounds__(NT, 2)
void vand_one(const float* __restrict__ Ag, const float* __restrict__ Bg,
              const float* __restrict__ Cg, __half* __restrict__ W2,
              float* __restrict__ out) {
    __shared__ __attribute__((aligned(16))) _Float16 As[2][BM * BK];  // 2x16KB
    __shared__ __attribute__((aligned(16))) _Float16 Bs[2][BN * BK];  // 2x16KB

    const int tid  = threadIdx.x;
    const int lane = tid & 63;
    const int w    = tid >> 6;
    const int wm   = w & 1, wn = w >> 1;
    const int m0   = blockIdx.y * BM;
    const int nb   = blockIdx.x * BN;
    const int lb   = blockIdx.x * (BN / 2);

    const float2* Ag2 = (const float2*)Ag;

    // ---------- phase 1: 512 W2 entries per block (R2-prep verbatim) ----------
    {
        const int blk = blockIdx.y * gridDim.x + blockIdx.x;   // 0..511
        const float2* B2 = (const float2*)Bg;
        const float2* C2 = (const float2*)Cg;
        #pragma unroll
        for (int i = 0; i < 2; ++i) {
            int e = blk * 512 + i * 256 + tid;                 // 0..262143
            int h = e >> 10, p = e & 1023;
            float2 a = Ag2[p];
            float er = __expf(a.x * DT);
            float s, c;
            __sincosf(a.y * DT, &s, &c);
            float nr = er * c - 1.0f, ni = er * s;
            float inv = 1.0f / (a.x * a.x + a.y * a.y);
            float sr = (nr * a.x + ni * a.y) * inv;
            float si = (ni * a.x - nr * a.y) * inv;
            float2 b  = B2[(size_t)p * H_DIM + h];
            float2 cc = C2[(size_t)h * P_DIM + p];
            float tr = cc.x * sr - cc.y * si, ti = cc.x * si + cc.y * sr;
            float wr = (tr * b.x - ti * b.y) * WSCALE;
            float wi = (tr * b.y + ti * b.x) * WSCALE;
            ((__half2*)W2)[e] = __float22half2_rn(make_float2(wr, wi));
        }
    }
    // ---------- device-scope barrier ----------
    __threadfence();                       // release: W2 stores visible device-wide
    if (tid == 0) {
        unsigned old = atomicAdd(&g_ctr, 1u);
        unsigned tgt = (old - (old & 511u)) + 512u;
        unsigned budget = 2000000u;        // bounded: failure mode = wrong answer, not hang
        while (atomicAdd(&g_ctr, 0u) < tgt && --budget) {
            __builtin_amdgcn_s_sleep(8);
        }
    }
    __syncthreads();
    __threadfence();                       // acquire: invalidate stale cached W2

    // ---------- phase 2: R3 main loop (verbatim) ----------
    f32x4 acc[4][4];
    #pragma unroll
    for (int mt = 0; mt < 4; ++mt)
        #pragma unroll
        for (int nt = 0; nt < 4; ++nt)
            acc[mt][nt] = (f32x4){0.f, 0.f, 0.f, 0.f};

    const int q    = tid & 15;
    const int llq  = (tid >> 4) << 2;
    const float l0f = (float)(lb + llq);
    const int grp  = q >> 1, sub = (q & 1) << 2;

    const int goff = (lane >> 3) * 2048 + (((lane & 7) ^ (lane >> 3)) << 3);
    const _Float16* gwbase = (const _Float16*)W2 + (size_t)(m0 + (w << 5)) * 2048;
    const int ldsoff = (w << 5) * 64;

    _Float16* Acur = &As[0][0]; _Float16* Bcur = &Bs[0][0];
    _Float16* Anxt = &As[1][0]; _Float16* Bnxt = &Bs[1][0];

#define DMA_CHUNK(K0, DST)                                                        \
    {                                                                             \
        const _Float16* gw = gwbase + (K0) + goff;                                \
        _Float16* lB = (DST) + ldsoff;                                            \
        _Pragma("unroll")                                                         \
        for (int r = 0; r < 4; ++r)                                               \
            __builtin_amdgcn_global_load_lds(GPTR(gw + r * 8 * 2048),             \
                                             LPTR(lB + r * 8 * 64), 16, 0, 0);    \
    }

#define VGEN_CHUNK(K0, DST)                                                       \
    {                                                                             \
        float2 a0 = Ag2[((K0) >> 1) + 2 * q];                                     \
        float2 a1 = Ag2[((K0) >> 1) + 2 * q + 1];                                 \
        float c0x = a0.x * DT, c0y = a0.y * (DT * INV2PI);                        \
        float c1x = a1.x * DT, c1y = a1.y * (DT * INV2PI);                        \
        float s, c;                                                               \
        float e0 = __expf(c0x); __sincosf(c0y * TWOPI, &s, &c);                   \
        float2 ab0 = make_float2(e0 * c, e0 * s);                                 \
        float e1 = __expf(c1x); __sincosf(c1y * TWOPI, &s, &c);                   \
        float2 ab1 = make_float2(e1 * c, e1 * s);                                 \
        float mg = __expf(c0x * l0f);                                             \
        float x = c0y * l0f; x -= rintf(x); __sincosf(x * TWOPI, &s, &c);         \
        float2 v0 = make_float2(mg * c, mg * s);                                  \
        mg = __expf(c1x * l0f);                                                   \
        x = c1y * l0f; x -= rintf(x); __sincosf(x * TWOPI, &s, &c);               \
        float2 v1 = make_float2(mg * c, mg * s);                                  \
        _Pragma("unroll")                                                         \
        for (int j = 0; j < 4; ++j) {                                             \
            int n0 = 2 * (llq + j);                                               \
            H2U h0u, h1u, h2u, h3u;                                               \
            h0u.h = __float22half2_rn(make_float2(v0.x, -v0.y));                  \
            h1u.h = __float22half2_rn(make_float2(v1.x, -v1.y));                  \
            h2u.h = __float22half2_rn(make_float2(v0.y, v0.x));                   \
            h3u.h = __float22half2_rn(make_float2(v1.y, v1.x));                   \
            int e0i = n0 * 64 + ((grp ^ (n0 & 7)) << 3) + sub;                    \
            int e1i = (n0 + 1) * 64 + ((grp ^ ((n0 + 1) & 7)) << 3) + sub;        \
            *(uint2*)((DST) + e0i) = make_uint2(h0u.u, h1u.u);                    \
            *(uint2*)((DST) + e1i) = make_uint2(h2u.u, h3u.u);                    \
            if (j < 3) { v0 = cmulf(v0, ab0); v1 = cmulf(v1, ab1); }              \
        }                                                                         \
    }

    DMA_CHUNK(0, Acur)
    VGEN_CHUNK(0, Bcur)
    __syncthreads();

    for (int kk = 0; kk < 32; ++kk) {
        if (kk < 31) {
            const int k1 = (kk + 1) * BK;
            DMA_CHUNK(k1, Anxt)
            VGEN_CHUNK(k1, Bnxt)
        }
        #pragma unroll
        for (int ks = 0; ks < 2; ++ks) {
            f16x8 af[4], bf[4];
            const int g = ks * 4 + (lane >> 4);
            #pragma unroll
            for (int t = 0; t < 4; ++t) {
                int m = wm * 64 + t * 16 + (lane & 15);
                af[t] = *(const f16x8*)(Acur + m * 64 + ((g ^ (m & 7)) << 3));
                int n = wn * 64 + t * 16 + (lane & 15);
                bf[t] = *(const f16x8*)(Bcur + n * 64 + ((g ^ (n & 7)) << 3));
            }
            #pragma unroll
            for (int mt = 0; mt < 4; ++mt)
                #pragma unroll
                for (int nt = 0; nt < 4; ++nt)
                    acc[mt][nt] = __builtin_amdgcn_mfma_f32_16x16x32_f16(
                        af[mt], bf[nt], acc[mt][nt], 0, 0, 0);
        }
        __syncthreads();
        _Float16* tA = Acur; Acur = Anxt; Anxt = tA;
        _Float16* tB = Bcur; Bcur = Bnxt; Bnxt = tB;
    }

    #pragma unroll
    for (int mt = 0; mt < 4; ++mt) {
        #pragma unroll
        for (int nt = 0; nt < 4; ++nt) {
            int h = m0 + wm * 64 + mt * 16 + ((lane >> 4) << 2);
            int n = nb + wn * 64 + nt * 16 + (lane & 15);
            #pragma unroll
            for (int r = 0; r < 4; ++r)
                out[(size_t)(h + r) * 32768 + n] = acc[mt][nt][r] * INVS;
        }
    }
#undef DMA_CHUNK
#undef VGEN_CHUNK
}

extern "C" void kernel_launch(void* const* d_in, const int* in_sizes, int n_in,
                              void* d_out, int out_size, void* d_ws, size_t ws_size,
                              hipStream_t stream) {
    const float* A = (const float*)d_in[0];   // (P, 2)
    const float* B = (const float*)d_in[1];   // (P, H, 2)
    const float* C = (const float*)d_in[2];   // (H, P, 2)
    float* out = (float*)d_out;               // (H, L, 2)
    __half* W2 = (__half*)d_ws;               // (256, 2048) fp16, 1 MB

    // 512 blocks = exactly 2 blocks/CU (LDS-bound) on 256 CUs -> co-resident,
    // required for the in-kernel device barrier.
    vand_one<<<dim3(L_DIM * 2 / BN, H_DIM / BM), dim3(NT), 0, stream>>>(
        A, B, C, W2, out);
}